// Round 14
// baseline (963.441 us; speedup 1.0000x reference)
//
#include <hip/hip_runtime.h>
#include <hip/hip_bf16.h>

typedef __attribute__((ext_vector_type(4))) float f32x4;
typedef __attribute__((ext_vector_type(8))) short s16x8;
typedef __attribute__((ext_vector_type(4))) short s16x4;
typedef __attribute__((ext_vector_type(2))) short s16x2;

#define MFMA_BF16 __builtin_amdgcn_mfma_f32_16x16x32_bf16

__device__ inline short f2bf(float f) {
  unsigned u = __float_as_uint(f);
  u = (u + 0x7FFFu + ((u >> 16) & 1u)) >> 16;
  return (short)u;
}
__device__ inline float bf2f(short s) {
  return __uint_as_float(((unsigned)(unsigned short)s) << 16);
}

#define DPPF(x, ctrl) __int_as_float(__builtin_amdgcn_update_dpp( \
    __float_as_int(x), __float_as_int(x), ctrl, 0xF, 0xF, false))
__device__ inline float rowmax16(float x) {
  x = fmaxf(x, DPPF(x, 0xB1));
  x = fmaxf(x, DPPF(x, 0x4E));
  x = fmaxf(x, DPPF(x, 0x124));
  x = fmaxf(x, DPPF(x, 0x128));
  return x;
}
__device__ inline float rowsum16(float x) {
  x += DPPF(x, 0xB1);
  x += DPPF(x, 0x4E);
  x += DPPF(x, 0x124);
  x += DPPF(x, 0x128);
  return x;
}

// XCD bx-stripe + supertile mapping (requires gx%8==0, gy%8==0).
__device__ inline void supertile_map(int gx, int gy, int& bx, int& by) {
  int orig = blockIdx.y * gx + blockIdx.x;
  int x   = orig & 7;
  int lin = orig >> 3;
  int sw  = gx >> 3;
  int bg  = lin / (sw * 8);
  int rem = lin % (sw * 8);
  bx = x * sw + (rem >> 3);
  by = bg * 8 + (rem & 7);
}

// ---------------- fp32 -> bf16 conversion (optional uniform scale) ----------
__global__ __launch_bounds__(256) void cvt_kernel(
    const float* __restrict__ in, short* __restrict__ out, int n, float scale)
{
  int idx = (blockIdx.x * 256 + threadIdx.x) * 8;
  if (idx >= n) return;
  f32x4 a = *(const f32x4*)(in + idx);
  f32x4 b = *(const f32x4*)(in + idx + 4);
  s16x8 o;
  #pragma unroll
  for (int j = 0; j < 4; ++j) { o[j] = f2bf(a[j] * scale); o[4 + j] = f2bf(b[j] * scale); }
  *(s16x8*)(out + idx) = o;
}

// ---------------- RMSNorm: fp32 in -> bf16 out, one row (2048) per block ----
__global__ __launch_bounds__(256) void rmsnorm_kernel(
    const float* __restrict__ x, const float* __restrict__ w, short* __restrict__ out)
{
  size_t row = blockIdx.x;
  const float* xr = x + row * 2048;
  int base = threadIdx.x * 8;
  f32x4 a = *(const f32x4*)(xr + base);
  f32x4 b = *(const f32x4*)(xr + base + 4);
  float ss = a[0]*a[0] + a[1]*a[1] + a[2]*a[2] + a[3]*a[3]
           + b[0]*b[0] + b[1]*b[1] + b[2]*b[2] + b[3]*b[3];
  #pragma unroll
  for (int off = 1; off < 64; off <<= 1) ss += __shfl_xor(ss, off, 64);
  __shared__ float red[4];
  if ((threadIdx.x & 63) == 0) red[threadIdx.x >> 6] = ss;
  __syncthreads();
  float tot = red[0] + red[1] + red[2] + red[3];
  float rn = rsqrtf(tot * (1.0f / 2048.0f) + 1e-6f) * 0.022097086912079608f;
  f32x4 wa = *(const f32x4*)(w + base);
  f32x4 wb = *(const f32x4*)(w + base + 4);
  s16x8 o;
  #pragma unroll
  for (int j = 0; j < 4; ++j) {
    o[j]     = f2bf(a[j] * wa[j] * rn);
    o[4 + j] = f2bf(b[j] * wb[j] * rn);
  }
  *(s16x8*)(out + row * 2048 + base) = o;
}

// ---------------- small GEMM (kv proj only): 128x128 m97 structure ----------
template <int MODE>
__global__ __launch_bounds__(256, 2) void gemm_bt_kernel(
    const short* __restrict__ A, const short* __restrict__ B,
    void* __restrict__ Cv, const float* __restrict__ resid,
    int M, int N, int K)
{
  __shared__ short As[128 * 32];
  __shared__ short Bs[128 * 32];
  int tid = threadIdx.x;
  int lane = tid & 63;
  int w = tid >> 6;
  int r = lane & 15, g = lane >> 4;
  int wr = w >> 1, wc = w & 1;
  size_t row0 = (size_t)blockIdx.y * 128;
  size_t col0 = (size_t)blockIdx.x * 128;

  f32x4 acc[4][4];
  #pragma unroll
  for (int i = 0; i < 4; ++i)
    #pragma unroll
    for (int j = 0; j < 4; ++j) acc[i][j] = (f32x4){0.f, 0.f, 0.f, 0.f};

  const short* Ablk = A + row0 * K;
  const short* Bblk = B + col0 * K;
  int arow = tid >> 2;
  int akk = (tid & 3) << 3;

  for (int k0 = 0; k0 < K; k0 += 32) {
    #pragma unroll
    for (int i = 0; i < 2; ++i) {
      int chunk = i * 256 + tid;
      int rr = i * 64 + arow;
      __builtin_amdgcn_global_load_lds(
          (const __attribute__((address_space(1))) unsigned int*)(Ablk + (size_t)rr * K + k0 + akk),
          (__attribute__((address_space(3))) unsigned int*)(&As[chunk * 8]), 16, 0, 0);
      __builtin_amdgcn_global_load_lds(
          (const __attribute__((address_space(1))) unsigned int*)(Bblk + (size_t)rr * K + k0 + akk),
          (__attribute__((address_space(3))) unsigned int*)(&Bs[chunk * 8]), 16, 0, 0);
    }
    __syncthreads();
    s16x8 af[4], bfr[4];
    #pragma unroll
    for (int mm = 0; mm < 4; ++mm)
      af[mm] = *(const s16x8*)(&As[(wr * 64 + mm * 16 + r) * 32 + g * 8]);
    #pragma unroll
    for (int nn = 0; nn < 4; ++nn)
      bfr[nn] = *(const s16x8*)(&Bs[(wc * 64 + nn * 16 + r) * 32 + g * 8]);
    #pragma unroll
    for (int mm = 0; mm < 4; ++mm)
      #pragma unroll
      for (int nn = 0; nn < 4; ++nn)
        acc[mm][nn] = MFMA_BF16(af[mm], bfr[nn], acc[mm][nn], 0, 0, 0);
    __syncthreads();
  }

  #pragma unroll
  for (int mm = 0; mm < 4; ++mm) {
    #pragma unroll
    for (int nn = 0; nn < 4; ++nn) {
      #pragma unroll
      for (int j = 0; j < 4; ++j) {
        size_t rr = row0 + wr * 64 + mm * 16 + g * 4 + j;
        size_t cc = col0 + wc * 64 + nn * 16 + r;
        size_t idx = rr * (size_t)N + cc;
        if constexpr (MODE == 0) {
          ((short*)Cv)[idx] = f2bf(acc[mm][nn][j]);
        } else {
          ((float*)Cv)[idx] = acc[mm][nn][j] + resid[idx];
        }
      }
    }
  }
}

#define BAR __builtin_amdgcn_s_barrier()

// ---------------- 256x128 BK=32 GEMM (w13-ratio; wq, wo, w2) ----------------
// 4 waves, wave tile 64x128 (acc 4x8), per tile per wave: 6 staging loads,
// 12 ds_read_b128, 32 MFMA -- identical instruction mix to gemm_w13 (proven
// 892 TF / 40% MfmaUtil). LDS 48KB -> 2 blocks/CU. vmcnt(6); swizzle
// chunk c ^= (row>>1)&3 (2-way max, free).

#define STG256(T, BASE, DST, NLOAD)                                            \
  _Pragma("unroll")                                                            \
  for (int i = 0; i < NLOAD; ++i) {                                            \
    int lc = i * 256 + tid;                                                    \
    int rw = lc >> 2, ch = lc & 3;                                             \
    __builtin_amdgcn_global_load_lds(                                          \
        (const __attribute__((address_space(1))) unsigned int*)                \
            (BASE + (size_t)rw * K + (T) * 32 + ((ch ^ ((rw >> 1) & 3)) << 3)),\
        (__attribute__((address_space(3))) unsigned int*)                      \
            (&DST[(T) & 1][lc * 8]), 16, 0, 0);                                \
  }

template <int MODE>
__global__ __launch_bounds__(256, 2) void gemm256_kernel(
    const short* __restrict__ A, const short* __restrict__ B,
    void* __restrict__ Cv, const float* __restrict__ resid,
    int M, int N, int K)
{
  __shared__ short As[2][256 * 32];
  __shared__ short Bs[2][128 * 32];

  int tid = threadIdx.x;
  int lane = tid & 63;
  int w = tid >> 6;          // wave owns rows [w*64, w*64+64)
  int r = lane & 15, g = lane >> 4;

  int bx, by;
  supertile_map(gridDim.x, gridDim.y, bx, by);
  size_t row0 = (size_t)by * 256;
  size_t col0 = (size_t)bx * 128;

  const short* Ablk = A + row0 * K;
  const short* Bblk = B + col0 * K;

  f32x4 acc[4][8];
  #pragma unroll
  for (int i = 0; i < 4; ++i)
    #pragma unroll
    for (int j = 0; j < 8; ++j) acc[i][j] = (f32x4){0.f, 0.f, 0.f, 0.f};

  s16x8 aR[4], bR[8];
  int NT = K >> 5;

  STG256(0, Ablk, As, 4); STG256(0, Bblk, Bs, 2);

  for (int t = 0; t < NT; ++t) {
    int d = t & 1;
    bool nl = (t < NT - 1);
    if (nl) {
      STG256(t + 1, Ablk, As, 4); STG256(t + 1, Bblk, Bs, 2);
      asm volatile("s_waitcnt vmcnt(6)" ::: "memory");  // tile t landed
    } else {
      asm volatile("s_waitcnt vmcnt(0)" ::: "memory");
    }
    BAR;
    #pragma unroll
    for (int mi = 0; mi < 4; ++mi) {
      int rowa = w * 64 + mi * 16 + r;
      aR[mi] = *(const s16x8*)(&As[d][rowa * 32 + ((g ^ ((rowa >> 1) & 3)) << 3)]);
    }
    #pragma unroll
    for (int ni = 0; ni < 8; ++ni) {
      int rowb = ni * 16 + r;
      bR[ni] = *(const s16x8*)(&Bs[d][rowb * 32 + ((g ^ ((rowb >> 1) & 3)) << 3)]);
    }
    __builtin_amdgcn_s_setprio(1);
    #pragma unroll
    for (int mi = 0; mi < 4; ++mi)
      #pragma unroll
      for (int ni = 0; ni < 8; ++ni)
        acc[mi][ni] = MFMA_BF16(aR[mi], bR[ni], acc[mi][ni], 0, 0, 0);
    __builtin_amdgcn_s_setprio(0);
    BAR;
  }

  #pragma unroll
  for (int mi = 0; mi < 4; ++mi) {
    #pragma unroll
    for (int ni = 0; ni < 8; ++ni) {
      #pragma unroll
      for (int j = 0; j < 4; ++j) {
        size_t rr = row0 + w * 64 + mi * 16 + g * 4 + j;
        size_t cc = col0 + ni * 16 + r;
        size_t idx = rr * (size_t)N + cc;
        if constexpr (MODE == 0) {
          ((short*)Cv)[idx] = f2bf(acc[mi][ni][j]);
        } else {
          ((float*)Cv)[idx] = acc[mi][ni][j] + resid[idx];
        }
      }
    }
  }
}

// ---------------- fused w1||w3 GEMM + SwiGLU epilogue -----------------------
#define STG13(T, BASE, DST)                                                    \
  _Pragma("unroll")                                                            \
  for (int i = 0; i < 2; ++i) {                                                \
    int lc = i * 256 + tid;                                                    \
    int rw = lc >> 2, ch = lc & 3;                                             \
    __builtin_amdgcn_global_load_lds(                                          \
        (const __attribute__((address_space(1))) unsigned int*)                \
            (BASE + (size_t)rw * K + (T) * 32 + ((ch ^ ((rw >> 1) & 3)) << 3)),\
        (__attribute__((address_space(3))) unsigned int*)                      \
            (&DST[(T) & 1][lc * 8]), 16, 0, 0);                                \
  }

__global__ __launch_bounds__(256, 2) void gemm_w13_kernel(
    const short* __restrict__ A, const short* __restrict__ B1,
    const short* __restrict__ B3, short* __restrict__ C,
    int M, int N, int K)
{
  __shared__ short As[2][128 * 32];
  __shared__ short B1s[2][128 * 32];
  __shared__ short B3s[2][128 * 32];

  int tid = threadIdx.x;
  int lane = tid & 63;
  int w = tid >> 6;
  int r = lane & 15, g = lane >> 4;
  int wr = w >> 1, wc = w & 1;

  int bx, by;
  supertile_map(gridDim.x, gridDim.y, bx, by);
  size_t row0 = (size_t)by * 128;
  size_t col0 = (size_t)bx * 128;

  const short* Ablk  = A  + row0 * K;
  const short* B1blk = B1 + col0 * K;
  const short* B3blk = B3 + col0 * K;

  f32x4 acc1[4][4], acc3[4][4];
  #pragma unroll
  for (int i = 0; i < 4; ++i)
    #pragma unroll
    for (int j = 0; j < 4; ++j) {
      acc1[i][j] = (f32x4){0.f, 0.f, 0.f, 0.f};
      acc3[i][j] = (f32x4){0.f, 0.f, 0.f, 0.f};
    }

  s16x8 aR[4], b1R[4], b3R[4];
  int NT = K >> 5;

  STG13(0, Ablk, As); STG13(0, B1blk, B1s); STG13(0, B3blk, B3s);

  for (int t = 0; t < NT; ++t) {
    int d = t & 1;
    bool nl = (t < NT - 1);
    if (nl) {
      STG13(t + 1, Ablk, As); STG13(t + 1, B1blk, B1s); STG13(t + 1, B3blk, B3s);
      asm volatile("s_waitcnt vmcnt(6)" ::: "memory");
    } else {
      asm volatile("s_waitcnt vmcnt(0)" ::: "memory");
    }
    BAR;
    #pragma unroll
    for (int mi = 0; mi < 4; ++mi) {
      int rowa = wr * 64 + mi * 16 + r;
      aR[mi] = *(const s16x8*)(&As[d][rowa * 32 + ((g ^ ((rowa >> 1) & 3)) << 3)]);
    }
    #pragma unroll
    for (int ni = 0; ni < 4; ++ni) {
      int rowb = wc * 64 + ni * 16 + r;
      b1R[ni] = *(const s16x8*)(&B1s[d][rowb * 32 + ((g ^ ((rowb >> 1) & 3)) << 3)]);
      b3R[ni] = *(const s16x8*)(&B3s[d][rowb * 32 + ((g ^ ((rowb >> 1) & 3)) << 3)]);
    }
    __builtin_amdgcn_s_setprio(1);
    #pragma unroll
    for (int mi = 0; mi < 4; ++mi)
      #pragma unroll
      for (int ni = 0; ni < 4; ++ni) {
        acc1[mi][ni] = MFMA_BF16(aR[mi], b1R[ni], acc1[mi][ni], 0, 0, 0);
        acc3[mi][ni] = MFMA_BF16(aR[mi], b3R[ni], acc3[mi][ni], 0, 0, 0);
      }
    __builtin_amdgcn_s_setprio(0);
    BAR;
  }

  #pragma unroll
  for (int mi = 0; mi < 4; ++mi) {
    #pragma unroll
    for (int ni = 0; ni < 4; ++ni) {
      #pragma unroll
      for (int j = 0; j < 4; ++j) {
        size_t rr = row0 + wr * 64 + mi * 16 + g * 4 + j;
        size_t cc = col0 + wc * 64 + ni * 16 + r;
        float gv = acc1[mi][ni][j];
        float sg = gv / (1.0f + __expf(-gv));
        C[rr * (size_t)N + cc] = f2bf(sg * acc3[mi][ni][j]);
      }
    }
  }
}

// ---------------- V transpose: kv[B*S,256] cols 128..255 -> [B][128][S] -----
__global__ __launch_bounds__(256) void transpose_v_kernel(
    const short* __restrict__ kv, short* __restrict__ vt)
{
  __shared__ short t[64][65];
  int b = blockIdx.z;
  int s0 = blockIdx.x * 64;
  int d0 = blockIdx.y * 64;
  int tid = threadIdx.x;
  #pragma unroll
  for (int i = 0; i < 16; ++i) {
    int e = i * 256 + tid;
    int sr = e >> 6, dc = e & 63;
    t[sr][dc] = kv[(size_t)(b * 2048 + s0 + sr) * 256 + 128 + d0 + dc];
  }
  __syncthreads();
  #pragma unroll
  for (int i = 0; i < 16; ++i) {
    int e = i * 256 + tid;
    int dr = e >> 6, sc = e & 63;
    vt[(size_t)b * 128 * 2048 + (size_t)(d0 + dr) * 2048 + s0 + sc] = t[sc][dr];
  }
}

// ---------------- Flash attention (MQA), LDS-staged K/V, 4 waves x 32 q-rows
__global__ __launch_bounds__(256, 2) void attn_kernel(
    const short* __restrict__ q, const short* __restrict__ kv,
    const short* __restrict__ vt, short* __restrict__ out)
{
  const int S = 2048;
  int tid = threadIdx.x;
  int w = tid >> 6;
  int lane = tid & 63;
  int r = lane & 15, g = lane >> 4;
  int h = blockIdx.y, b = blockIdx.z;
  int qrow0 = blockIdx.x * 128 + w * 32;

  __shared__ short Ks[2][4096];
  __shared__ short Vs[2][4096];
  __shared__ short Ps[4][32][40];

  const short* kvsrc = kv + (size_t)b * S * 256;
  const short* vsrc  = vt + (size_t)b * 128 * S;

  const short* qbase = q + ((size_t)(b * S + qrow0 + r)) * 2048 + h * 128;
  s16x8 qa[2][4];
  #pragma unroll
  for (int gq = 0; gq < 2; ++gq)
    #pragma unroll
    for (int dc = 0; dc < 4; ++dc)
      qa[gq][dc] = *(const s16x8*)(qbase + gq * 16 * 2048 + dc * 32 + g * 8);

  f32x4 o[2][8];
  #pragma unroll
  for (int gq = 0; gq < 2; ++gq)
    #pragma unroll
    for (int dt = 0; dt < 8; ++dt) o[gq][dt] = (f32x4){0.f, 0.f, 0.f, 0.f};
  float m[2][4], l[2][4];
  #pragma unroll
  for (int gq = 0; gq < 2; ++gq)
    #pragma unroll
    for (int j = 0; j < 4; ++j) { m[gq][j] = -1e30f; l[gq][j] = 0.f; }

#define STAGE(KVT, BSEL)                                                        \
  {                                                                             \
    int kv0s = (KVT) * 32;                                                      \
    _Pragma("unroll")                                                           \
    for (int i = 0; i < 2; ++i) {                                               \
      int c = w * 64 + lane + i * 256;                                          \
      int krow = c >> 4, kcp = c & 15;                                          \
      __builtin_amdgcn_global_load_lds(                                         \
          (const __attribute__((address_space(1))) unsigned int*)               \
              (kvsrc + (size_t)(kv0s + krow) * 256 + ((kcp ^ (krow & 7)) << 3)),\
          (__attribute__((address_space(3))) unsigned int*)(&Ks[BSEL][c * 8]),  \
          16, 0, 0);                                                            \
      int vrow = c >> 2, vcp = c & 3;                                           \
      __builtin_amdgcn_global_load_lds(                                         \
          (const __attribute__((address_space(1))) unsigned int*)               \
              (vsrc + (size_t)vrow * S + kv0s + ((vcp ^ (vrow & 3)) << 3)),     \
          (__attribute__((address_space(3))) unsigned int*)(&Vs[BSEL][c * 8]),  \
          16, 0, 0);                                                            \
    }                                                                           \
  }

  STAGE(0, 0);
  __syncthreads();

  for (int it = 0; it < 64; ++it) {
    int cur = it & 1;
    if (it < 63) STAGE(it + 1, cur ^ 1);

    s16x8 kc0[4], kc1[4], vb[8];
    #pragma unroll
    for (int dc = 0; dc < 4; ++dc) {
      kc0[dc] = *(const s16x8*)(&Ks[cur][r * 128 + (((dc * 4 + g) ^ (r & 7)) << 3)]);
      kc1[dc] = *(const s16x8*)(&Ks[cur][(16 + r) * 128 + (((dc * 4 + g) ^ (r & 7)) << 3)]);
    }
    #pragma unroll
    for (int dt = 0; dt < 8; ++dt)
      vb[dt] = *(const s16x8*)(&Vs[cur][(dt * 16 + r) * 32 + ((g ^ (r & 3)) << 3)]);

    f32x4 sc0[2], sc1[2];
    #pragma unroll
    for (int gq = 0; gq < 2; ++gq) { sc0[gq] = (f32x4){0.f,0.f,0.f,0.f}; sc1[gq] = (f32x4){0.f,0.f,0.f,0.f}; }
    __builtin_amdgcn_s_setprio(1);
    #pragma unroll
    for (int dc = 0; dc < 4; ++dc) {
      #pragma unroll
      for (int gq = 0; gq < 2; ++gq) {
        sc0[gq] = MFMA_BF16(qa[gq][dc], kc0[dc], sc0[gq], 0, 0, 0);
        sc1[gq] = MFMA_BF16(qa[gq][dc], kc1[dc], sc1[gq], 0, 0, 0);
      }
    }
    __builtin_amdgcn_s_setprio(0);

    float p0[2][4], p1[2][4];
    #pragma unroll
    for (int gq = 0; gq < 2; ++gq) {
      float mx[4];
      #pragma unroll
      for (int j = 0; j < 4; ++j) mx[j] = rowmax16(fmaxf(sc0[gq][j], sc1[gq][j]));
      bool nd = (mx[0] > m[gq][0] + 8.f) | (mx[1] > m[gq][1] + 8.f)
              | (mx[2] > m[gq][2] + 8.f) | (mx[3] > m[gq][3] + 8.f);
      if (__any(nd)) {
        #pragma unroll
        for (int j = 0; j < 4; ++j) {
          float mn = fmaxf(m[gq][j], mx[j]);
          float alpha = __expf(m[gq][j] - mn);
          m[gq][j] = mn;
          l[gq][j] *= alpha;
          #pragma unroll
          for (int dt = 0; dt < 8; ++dt) o[gq][dt][j] *= alpha;
        }
      }
      #pragma unroll
      for (int j = 0; j < 4; ++j) {
        p0[gq][j] = __expf(sc0[gq][j] - m[gq][j]);
        p1[gq][j] = __expf(sc1[gq][j] - m[gq][j]);
        l[gq][j] += p0[gq][j] + p1[gq][j];
      }
      #pragma unroll
      for (int j = 0; j < 4; ++j) {
        Ps[w][gq * 16 + g * 4 + j][r]      = f2bf(p0[gq][j]);
        Ps[w][gq * 16 + g * 4 + j][16 + r] = f2bf(p1[gq][j]);
      }
    }
    asm volatile("s_waitcnt lgkmcnt(0)" ::: "memory");
    __builtin_amdgcn_sched_barrier(0);
    s16x8 pa0 = *(const s16x8*)(&Ps[w][r][g * 8]);
    s16x8 pa1 = *(const s16x8*)(&Ps[w][16 + r][g * 8]);
    __builtin_amdgcn_s_setprio(1);
    #pragma unroll
    for (int dt = 0; dt < 8; ++dt) {
      o[0][dt] = MFMA_BF16(pa0, vb[dt], o[0][dt], 0, 0, 0);
      o[1][dt] = MFMA_BF16(pa1, vb[dt], o[1][dt], 0, 0, 0);
    }
    __builtin_amdgcn_s_setprio(0);
    __syncthreads();
  }

  #pragma unroll
  for (int gq = 0; gq < 2; ++gq) {
    float linv[4];
    #pragma unroll
    for (int j = 0; j < 4; ++j) linv[j] = 1.0f / rowsum16(l[gq][j]);
    short* ob = out + ((size_t)(b * S + qrow0 + gq * 16)) * 2048 + h * 128;
    #pragma unroll
    for (int dt = 0; dt < 8; ++dt)
      #pragma unroll
      for (int j = 0; j < 4; ++j)
        ob[(size_t)(g * 4 + j) * 2048 + dt * 16 + r] = f2bf(o[gq][dt][j] * linv[j]);
  }
#undef STAGE
}

extern "C" void kernel_launch(void* const* d_in, const int* in_sizes, int n_in,
                              void* d_out, int out_size, void* d_ws, size_t ws_size,
                              hipStream_t stream) {
  const float* x   = (const float*)d_in[0];
  const float* n1w = (const float*)d_in[1];
  const float* wq  = (const float*)d_in[2];
  const float* wk  = (const float*)d_in[3];
  const float* wv  = (const float*)d_in[4];
  const float* wo  = (const float*)d_in[5];
  const float* n2w = (const float*)d_in[6];
  const float* w1  = (const float*)d_in[7];
  const float* w2  = (const float*)d_in[8];
  const float* w3  = (const float*)d_in[9];
  float* out = (float*)d_out;   // doubles as fp32 xmid buffer
  char* ws = (char*)d_ws;
  const size_t MB = 1ull << 20;
  short* wqb  = (short*)(ws);              //  8 MB (pre-scaled by 1/sqrt(128))
  short* wob  = (short*)(ws + 8 * MB);     //  8 MB
  short* w1b  = (short*)(ws + 16 * MB);    // 32 MB
  short* w2b  = (short*)(ws + 48 * MB);    // 32 MB
  short* w3b  = (short*)(ws + 80 * MB);    // 32 MB
  short* wkvb = (short*)(ws + 112 * MB);   //  1 MB [256,2048]
  short* h1   = (short*)(ws + 113 * MB);   // 16 MB
  short* gbuf = (short*)(ws + 129 * MB);   // 64 MB; overlays qb/kvb/vtb
  short* qb   = (short*)(ws + 129 * MB);   // 16 MB
  short* kvb  = (short*)(ws + 145 * MB);   //  2 MB
  short* vtb  = (short*)(ws + 147 * MB);   //  1 MB

  const float qscale = 0.08838834764831845f;  // 1/sqrt(128) folded into wq
  cvt_kernel<<<2048, 256, 0, stream>>>(wq, wqb, 4194304, qscale);
  cvt_kernel<<<128,  256, 0, stream>>>(wk, wkvb, 262144, 1.0f);
  cvt_kernel<<<128,  256, 0, stream>>>(wv, wkvb + 262144, 262144, 1.0f);
  cvt_kernel<<<2048, 256, 0, stream>>>(wo, wob, 4194304, 1.0f);
  cvt_kernel<<<8192, 256, 0, stream>>>(w1, w1b, 16777216, 1.0f);
  cvt_kernel<<<8192, 256, 0, stream>>>(w2, w2b, 16777216, 1.0f);
  cvt_kernel<<<8192, 256, 0, stream>>>(w3, w3b, 16777216, 1.0f);

  rmsnorm_kernel<<<4096, 256, 0, stream>>>(x, n1w, h1);
  gemm256_kernel<0><<<dim3(16, 16), 256, 0, stream>>>(h1, wqb, qb, nullptr, 4096, 2048, 2048);
  gemm_bt_kernel<0><<<dim3(2, 32), 256, 0, stream>>>(h1, wkvb, kvb, nullptr, 4096, 256, 2048);
  transpose_v_kernel<<<dim3(32, 2, 2), 256, 0, stream>>>(kvb, vtb);
  attn_kernel<<<dim3(16, 16, 2), 256, 0, stream>>>(qb, kvb, vtb, h1);
  gemm256_kernel<1><<<dim3(16, 16), 256, 0, stream>>>(h1, wob, out, x, 4096, 2048, 2048);
  rmsnorm_kernel<<<4096, 256, 0, stream>>>(out, n2w, h1);
  gemm_w13_kernel<<<dim3(64, 32), 256, 0, stream>>>(h1, w1b, w3b, gbuf, 4096, 8192, 2048);
  gemm256_kernel<1><<<dim3(16, 16), 256, 0, stream>>>(gbuf, w2b, out, out, 4096, 2048, 8192);
}

// Round 15
// 787.930 us; speedup vs baseline: 1.2227x; 1.2227x over previous
//
#include <hip/hip_runtime.h>
#include <hip/hip_bf16.h>

typedef __attribute__((ext_vector_type(4))) float f32x4;
typedef __attribute__((ext_vector_type(8))) short s16x8;
typedef __attribute__((ext_vector_type(4))) short s16x4;
typedef __attribute__((ext_vector_type(2))) short s16x2;

#define MFMA_BF16 __builtin_amdgcn_mfma_f32_16x16x32_bf16

__device__ inline short f2bf(float f) {
  unsigned u = __float_as_uint(f);
  u = (u + 0x7FFFu + ((u >> 16) & 1u)) >> 16;
  return (short)u;
}
__device__ inline float bf2f(short s) {
  return __uint_as_float(((unsigned)(unsigned short)s) << 16);
}

#define DPPF(x, ctrl) __int_as_float(__builtin_amdgcn_update_dpp( \
    __float_as_int(x), __float_as_int(x), ctrl, 0xF, 0xF, false))
__device__ inline float rowmax16(float x) {
  x = fmaxf(x, DPPF(x, 0xB1));
  x = fmaxf(x, DPPF(x, 0x4E));
  x = fmaxf(x, DPPF(x, 0x124));
  x = fmaxf(x, DPPF(x, 0x128));
  return x;
}
__device__ inline float rowsum16(float x) {
  x += DPPF(x, 0xB1);
  x += DPPF(x, 0x4E);
  x += DPPF(x, 0x124);
  x += DPPF(x, 0x128);
  return x;
}

// XCD bx-stripe + supertile mapping (requires gx%8==0, gy%8==0).
__device__ inline void supertile_map(int gx, int gy, int& bx, int& by) {
  int orig = blockIdx.y * gx + blockIdx.x;
  int x   = orig & 7;
  int lin = orig >> 3;
  int sw  = gx >> 3;
  int bg  = lin / (sw * 8);
  int rem = lin % (sw * 8);
  bx = x * sw + (rem >> 3);
  by = bg * 8 + (rem & 7);
}

// ---------------- fp32 -> bf16 conversion (optional uniform scale) ----------
__global__ __launch_bounds__(256) void cvt_kernel(
    const float* __restrict__ in, short* __restrict__ out, int n, float scale)
{
  int idx = (blockIdx.x * 256 + threadIdx.x) * 8;
  if (idx >= n) return;
  f32x4 a = *(const f32x4*)(in + idx);
  f32x4 b = *(const f32x4*)(in + idx + 4);
  s16x8 o;
  #pragma unroll
  for (int j = 0; j < 4; ++j) { o[j] = f2bf(a[j] * scale); o[4 + j] = f2bf(b[j] * scale); }
  *(s16x8*)(out + idx) = o;
}

// ---------------- RMSNorm: fp32 in -> bf16 out, one row (2048) per block ----
__global__ __launch_bounds__(256) void rmsnorm_kernel(
    const float* __restrict__ x, const float* __restrict__ w, short* __restrict__ out)
{
  size_t row = blockIdx.x;
  const float* xr = x + row * 2048;
  int base = threadIdx.x * 8;
  f32x4 a = *(const f32x4*)(xr + base);
  f32x4 b = *(const f32x4*)(xr + base + 4);
  float ss = a[0]*a[0] + a[1]*a[1] + a[2]*a[2] + a[3]*a[3]
           + b[0]*b[0] + b[1]*b[1] + b[2]*b[2] + b[3]*b[3];
  #pragma unroll
  for (int off = 1; off < 64; off <<= 1) ss += __shfl_xor(ss, off, 64);
  __shared__ float red[4];
  if ((threadIdx.x & 63) == 0) red[threadIdx.x >> 6] = ss;
  __syncthreads();
  float tot = red[0] + red[1] + red[2] + red[3];
  float rn = rsqrtf(tot * (1.0f / 2048.0f) + 1e-6f) * 0.022097086912079608f;
  f32x4 wa = *(const f32x4*)(w + base);
  f32x4 wb = *(const f32x4*)(w + base + 4);
  s16x8 o;
  #pragma unroll
  for (int j = 0; j < 4; ++j) {
    o[j]     = f2bf(a[j] * wa[j] * rn);
    o[4 + j] = f2bf(b[j] * wb[j] * rn);
  }
  *(s16x8*)(out + row * 2048 + base) = o;
}

// ---------------- small GEMM (kv proj only): 128x128 m97 structure ----------
template <int MODE>
__global__ __launch_bounds__(256, 2) void gemm_bt_kernel(
    const short* __restrict__ A, const short* __restrict__ B,
    void* __restrict__ Cv, const float* __restrict__ resid,
    int M, int N, int K)
{
  __shared__ short As[128 * 32];
  __shared__ short Bs[128 * 32];
  int tid = threadIdx.x;
  int lane = tid & 63;
  int w = tid >> 6;
  int r = lane & 15, g = lane >> 4;
  int wr = w >> 1, wc = w & 1;
  size_t row0 = (size_t)blockIdx.y * 128;
  size_t col0 = (size_t)blockIdx.x * 128;

  f32x4 acc[4][4];
  #pragma unroll
  for (int i = 0; i < 4; ++i)
    #pragma unroll
    for (int j = 0; j < 4; ++j) acc[i][j] = (f32x4){0.f, 0.f, 0.f, 0.f};

  const short* Ablk = A + row0 * K;
  const short* Bblk = B + col0 * K;
  int arow = tid >> 2;
  int akk = (tid & 3) << 3;

  for (int k0 = 0; k0 < K; k0 += 32) {
    #pragma unroll
    for (int i = 0; i < 2; ++i) {
      int chunk = i * 256 + tid;
      int rr = i * 64 + arow;
      __builtin_amdgcn_global_load_lds(
          (const __attribute__((address_space(1))) unsigned int*)(Ablk + (size_t)rr * K + k0 + akk),
          (__attribute__((address_space(3))) unsigned int*)(&As[chunk * 8]), 16, 0, 0);
      __builtin_amdgcn_global_load_lds(
          (const __attribute__((address_space(1))) unsigned int*)(Bblk + (size_t)rr * K + k0 + akk),
          (__attribute__((address_space(3))) unsigned int*)(&Bs[chunk * 8]), 16, 0, 0);
    }
    __syncthreads();
    s16x8 af[4], bfr[4];
    #pragma unroll
    for (int mm = 0; mm < 4; ++mm)
      af[mm] = *(const s16x8*)(&As[(wr * 64 + mm * 16 + r) * 32 + g * 8]);
    #pragma unroll
    for (int nn = 0; nn < 4; ++nn)
      bfr[nn] = *(const s16x8*)(&Bs[(wc * 64 + nn * 16 + r) * 32 + g * 8]);
    #pragma unroll
    for (int mm = 0; mm < 4; ++mm)
      #pragma unroll
      for (int nn = 0; nn < 4; ++nn)
        acc[mm][nn] = MFMA_BF16(af[mm], bfr[nn], acc[mm][nn], 0, 0, 0);
    __syncthreads();
  }

  #pragma unroll
  for (int mm = 0; mm < 4; ++mm) {
    #pragma unroll
    for (int nn = 0; nn < 4; ++nn) {
      #pragma unroll
      for (int j = 0; j < 4; ++j) {
        size_t rr = row0 + wr * 64 + mm * 16 + g * 4 + j;
        size_t cc = col0 + wc * 64 + nn * 16 + r;
        size_t idx = rr * (size_t)N + cc;
        if constexpr (MODE == 0) {
          ((short*)Cv)[idx] = f2bf(acc[mm][nn][j]);
        } else {
          ((float*)Cv)[idx] = acc[mm][nn][j] + resid[idx];
        }
      }
    }
  }
}

#define BAR __builtin_amdgcn_s_barrier()

// ---------------- 128x128 BK=64 GEMM, 2 blocks/CU (wq, wo, w2) --------------
// R12 config (best known): plain XCD swizzle, dbuf, vmcnt(8).
#define STAGEA1(T)                                                             \
  _Pragma("unroll")                                                            \
  for (int i = 0; i < 4; ++i) {                                                \
    int lc = i * 256 + tid;                                                    \
    int rw = lc >> 3, ch = lc & 7;                                             \
    __builtin_amdgcn_global_load_lds(                                          \
        (const __attribute__((address_space(1))) unsigned int*)                \
            (Ablk + (size_t)rw * K + (T) * 64 + ((ch ^ (rw & 7)) << 3)),       \
        (__attribute__((address_space(3))) unsigned int*)                      \
            (&As[(T) & 1][lc * 8]), 16, 0, 0);                                 \
  }

#define STAGEB1(T)                                                             \
  _Pragma("unroll")                                                            \
  for (int i = 0; i < 4; ++i) {                                                \
    int lc = i * 256 + tid;                                                    \
    int rw = lc >> 3, ch = lc & 7;                                             \
    __builtin_amdgcn_global_load_lds(                                          \
        (const __attribute__((address_space(1))) unsigned int*)                \
            (Bblk + (size_t)rw * K + (T) * 64 + ((ch ^ (rw & 7)) << 3)),       \
        (__attribute__((address_space(3))) unsigned int*)                      \
            (&Bs[(T) & 1][lc * 8]), 16, 0, 0);                                 \
  }

#define LDK(KS, D)                                                             \
  _Pragma("unroll")                                                            \
  for (int mi = 0; mi < 4; ++mi) {                                             \
    int rowa = wr * 64 + mi * 16 + r;                                          \
    aR[mi] = *(const s16x8*)(&As[D][rowa * 64 + (((KS) * 4 + g) ^ (rowa & 7)) * 8]); \
  }                                                                            \
  _Pragma("unroll")                                                            \
  for (int ni = 0; ni < 4; ++ni) {                                             \
    int rowb = wc * 64 + ni * 16 + r;                                          \
    bR[ni] = *(const s16x8*)(&Bs[D][rowb * 64 + (((KS) * 4 + g) ^ (rowb & 7)) * 8]); \
  }

#define MF16A                                                                  \
  __builtin_amdgcn_s_setprio(1);                                               \
  _Pragma("unroll")                                                            \
  for (int mi = 0; mi < 4; ++mi)                                               \
    _Pragma("unroll")                                                          \
    for (int ni = 0; ni < 4; ++ni)                                             \
      acc[mi][ni] = MFMA_BF16(aR[mi], bR[ni], acc[mi][ni], 0, 0, 0);           \
  __builtin_amdgcn_s_setprio(0);

template <int MODE>
__global__ __launch_bounds__(256, 2) void gemm128_kernel(
    const short* __restrict__ A, const short* __restrict__ B,
    void* __restrict__ Cv, const float* __restrict__ resid,
    int M, int N, int K)
{
  __shared__ short As[2][128 * 64];
  __shared__ short Bs[2][128 * 64];

  int tid = threadIdx.x;
  int lane = tid & 63;
  int w = tid >> 6;
  int r = lane & 15, g = lane >> 4;
  int wr = w >> 1, wc = w & 1;

  int nwg = gridDim.x * gridDim.y;
  int orig = blockIdx.y * gridDim.x + blockIdx.x;
  int swz = (orig & 7) * (nwg >> 3) + (orig >> 3);
  int bx = swz % gridDim.x, by = swz / gridDim.x;
  size_t row0 = (size_t)by * 128;
  size_t col0 = (size_t)bx * 128;

  const short* Ablk = A + row0 * K;
  const short* Bblk = B + col0 * K;

  f32x4 acc[4][4];
  #pragma unroll
  for (int i = 0; i < 4; ++i)
    #pragma unroll
    for (int j = 0; j < 4; ++j) acc[i][j] = (f32x4){0.f, 0.f, 0.f, 0.f};

  s16x8 aR[4], bR[4];
  int NT = K >> 6;

  STAGEA1(0); STAGEB1(0);

  for (int t = 0; t < NT; ++t) {
    int d = t & 1;
    bool nl = (t < NT - 1);
    if (nl) {
      STAGEA1(t + 1); STAGEB1(t + 1);
      asm volatile("s_waitcnt vmcnt(8)" ::: "memory");
    } else {
      asm volatile("s_waitcnt vmcnt(0)" ::: "memory");
    }
    BAR;
    LDK(0, d);
    MF16A;
    LDK(1, d);
    MF16A;
    BAR;
  }

  #pragma unroll
  for (int mi = 0; mi < 4; ++mi) {
    #pragma unroll
    for (int ni = 0; ni < 4; ++ni) {
      #pragma unroll
      for (int j = 0; j < 4; ++j) {
        size_t rr = row0 + wr * 64 + mi * 16 + g * 4 + j;
        size_t cc = col0 + wc * 64 + ni * 16 + r;
        size_t idx = rr * (size_t)N + cc;
        if constexpr (MODE == 0) {
          ((short*)Cv)[idx] = f2bf(acc[mi][ni][j]);
        } else {
          ((float*)Cv)[idx] = acc[mi][ni][j] + resid[idx];
        }
      }
    }
  }
}

// ---------------- fused w1||w3 GEMM + SwiGLU, 3-buffer depth-2 prefetch -----
// 128x128 tile, BK=32, A staged once; tiles t+1,t+2 in flight -> issue-to-wait
// distance ~2 tiles (covers ~900cy HBM latency). Steady vmcnt(12)
// (18 outstanding - 6 = tile t landed); tail 6 -> 0. LDS 72KB -> 2 blocks/CU.

#define STG13(T, D, BASE, DST)                                                 \
  _Pragma("unroll")                                                            \
  for (int i = 0; i < 2; ++i) {                                                \
    int lc = i * 256 + tid;                                                    \
    int rw = lc >> 2, ch = lc & 3;                                             \
    __builtin_amdgcn_global_load_lds(                                          \
        (const __attribute__((address_space(1))) unsigned int*)                \
            (BASE + (size_t)rw * K + (T) * 32 + ((ch ^ ((rw >> 1) & 3)) << 3)),\
        (__attribute__((address_space(3))) unsigned int*)                      \
            (&DST[D][lc * 8]), 16, 0, 0);                                      \
  }

__global__ __launch_bounds__(256, 2) void gemm_w13_kernel(
    const short* __restrict__ A, const short* __restrict__ B1,
    const short* __restrict__ B3, short* __restrict__ C,
    int M, int N, int K)
{
  __shared__ short As[3][128 * 32];
  __shared__ short B1s[3][128 * 32];
  __shared__ short B3s[3][128 * 32];

  int tid = threadIdx.x;
  int lane = tid & 63;
  int w = tid >> 6;
  int r = lane & 15, g = lane >> 4;
  int wr = w >> 1, wc = w & 1;

  int bx, by;
  supertile_map(gridDim.x, gridDim.y, bx, by);
  size_t row0 = (size_t)by * 128;
  size_t col0 = (size_t)bx * 128;

  const short* Ablk  = A  + row0 * K;
  const short* B1blk = B1 + col0 * K;
  const short* B3blk = B3 + col0 * K;

  f32x4 acc1[4][4], acc3[4][4];
  #pragma unroll
  for (int i = 0; i < 4; ++i)
    #pragma unroll
    for (int j = 0; j < 4; ++j) {
      acc1[i][j] = (f32x4){0.f, 0.f, 0.f, 0.f};
      acc3[i][j] = (f32x4){0.f, 0.f, 0.f, 0.f};
    }

  s16x8 aR[4], b1R[4], b3R[4];
  int NT = K >> 5;

  // prologue: stage tiles 0 and 1 (12 loads outstanding)
  STG13(0, 0, Ablk, As); STG13(0, 0, B1blk, B1s); STG13(0, 0, B3blk, B3s);
  STG13(1, 1, Ablk, As); STG13(1, 1, B1blk, B1s); STG13(1, 1, B3blk, B3s);

  int bcur = 0, bstg = 2;
  for (int t = 0; t < NT; ++t) {
    if (t + 2 < NT) {
      STG13(t + 2, bstg, Ablk, As);
      STG13(t + 2, bstg, B1blk, B1s);
      STG13(t + 2, bstg, B3blk, B3s);
      asm volatile("s_waitcnt vmcnt(12)" ::: "memory");  // tile t landed
    } else if (t + 1 < NT) {
      asm volatile("s_waitcnt vmcnt(6)" ::: "memory");
    } else {
      asm volatile("s_waitcnt vmcnt(0)" ::: "memory");
    }
    BAR;
    #pragma unroll
    for (int mi = 0; mi < 4; ++mi) {
      int rowa = wr * 64 + mi * 16 + r;
      aR[mi] = *(const s16x8*)(&As[bcur][rowa * 32 + ((g ^ ((rowa >> 1) & 3)) << 3)]);
    }
    #pragma unroll
    for (int ni = 0; ni < 4; ++ni) {
      int rowb = wc * 64 + ni * 16 + r;
      b1R[ni] = *(const s16x8*)(&B1s[bcur][rowb * 32 + ((g ^ ((rowb >> 1) & 3)) << 3)]);
      b3R[ni] = *(const s16x8*)(&B3s[bcur][rowb * 32 + ((g ^ ((rowb >> 1) & 3)) << 3)]);
    }
    __builtin_amdgcn_s_setprio(1);
    #pragma unroll
    for (int mi = 0; mi < 4; ++mi)
      #pragma unroll
      for (int ni = 0; ni < 4; ++ni) {
        acc1[mi][ni] = MFMA_BF16(aR[mi], b1R[ni], acc1[mi][ni], 0, 0, 0);
        acc3[mi][ni] = MFMA_BF16(aR[mi], b3R[ni], acc3[mi][ni], 0, 0, 0);
      }
    __builtin_amdgcn_s_setprio(0);
    BAR;
    bcur = (bcur == 2) ? 0 : bcur + 1;
    bstg = (bstg == 2) ? 0 : bstg + 1;
  }

  // epilogue: silu(acc1) * acc3 -> bf16
  #pragma unroll
  for (int mi = 0; mi < 4; ++mi) {
    #pragma unroll
    for (int ni = 0; ni < 4; ++ni) {
      #pragma unroll
      for (int j = 0; j < 4; ++j) {
        size_t rr = row0 + wr * 64 + mi * 16 + g * 4 + j;
        size_t cc = col0 + wc * 64 + ni * 16 + r;
        float gv = acc1[mi][ni][j];
        float sg = gv / (1.0f + __expf(-gv));
        C[rr * (size_t)N + cc] = f2bf(sg * acc3[mi][ni][j]);
      }
    }
  }
}

// ---------------- V transpose: kv[B*S,256] cols 128..255 -> [B][128][S] -----
__global__ __launch_bounds__(256) void transpose_v_kernel(
    const short* __restrict__ kv, short* __restrict__ vt)
{
  __shared__ short t[64][65];
  int b = blockIdx.z;
  int s0 = blockIdx.x * 64;
  int d0 = blockIdx.y * 64;
  int tid = threadIdx.x;
  #pragma unroll
  for (int i = 0; i < 16; ++i) {
    int e = i * 256 + tid;
    int sr = e >> 6, dc = e & 63;
    t[sr][dc] = kv[(size_t)(b * 2048 + s0 + sr) * 256 + 128 + d0 + dc];
  }
  __syncthreads();
  #pragma unroll
  for (int i = 0; i < 16; ++i) {
    int e = i * 256 + tid;
    int dr = e >> 6, sc = e & 63;
    vt[(size_t)b * 128 * 2048 + (size_t)(d0 + dr) * 2048 + s0 + sc] = t[sc][dr];
  }
}

// ---------------- Flash attention (MQA), LDS-staged K/V, 4 waves x 32 q-rows
__global__ __launch_bounds__(256, 2) void attn_kernel(
    const short* __restrict__ q, const short* __restrict__ kv,
    const short* __restrict__ vt, short* __restrict__ out)
{
  const int S = 2048;
  int tid = threadIdx.x;
  int w = tid >> 6;
  int lane = tid & 63;
  int r = lane & 15, g = lane >> 4;
  int h = blockIdx.y, b = blockIdx.z;
  int qrow0 = blockIdx.x * 128 + w * 32;

  __shared__ short Ks[2][4096];
  __shared__ short Vs[2][4096];
  __shared__ short Ps[4][32][40];

  const short* kvsrc = kv + (size_t)b * S * 256;
  const short* vsrc  = vt + (size_t)b * 128 * S;

  const short* qbase = q + ((size_t)(b * S + qrow0 + r)) * 2048 + h * 128;
  s16x8 qa[2][4];
  #pragma unroll
  for (int gq = 0; gq < 2; ++gq)
    #pragma unroll
    for (int dc = 0; dc < 4; ++dc)
      qa[gq][dc] = *(const s16x8*)(qbase + gq * 16 * 2048 + dc * 32 + g * 8);

  f32x4 o[2][8];
  #pragma unroll
  for (int gq = 0; gq < 2; ++gq)
    #pragma unroll
    for (int dt = 0; dt < 8; ++dt) o[gq][dt] = (f32x4){0.f, 0.f, 0.f, 0.f};
  float m[2][4], l[2][4];
  #pragma unroll
  for (int gq = 0; gq < 2; ++gq)
    #pragma unroll
    for (int j = 0; j < 4; ++j) { m[gq][j] = -1e30f; l[gq][j] = 0.f; }

#define STAGE(KVT, BSEL)                                                        \
  {                                                                             \
    int kv0s = (KVT) * 32;                                                      \
    _Pragma("unroll")                                                           \
    for (int i = 0; i < 2; ++i) {                                               \
      int c = w * 64 + lane + i * 256;                                          \
      int krow = c >> 4, kcp = c & 15;                                          \
      __builtin_amdgcn_global_load_lds(                                         \
          (const __attribute__((address_space(1))) unsigned int*)               \
              (kvsrc + (size_t)(kv0s + krow) * 256 + ((kcp ^ (krow & 7)) << 3)),\
          (__attribute__((address_space(3))) unsigned int*)(&Ks[BSEL][c * 8]),  \
          16, 0, 0);                                                            \
      int vrow = c >> 2, vcp = c & 3;                                           \
      __builtin_amdgcn_global_load_lds(                                         \
          (const __attribute__((address_space(1))) unsigned int*)               \
              (vsrc + (size_t)vrow * S + kv0s + ((vcp ^ (vrow & 3)) << 3)),     \
          (__attribute__((address_space(3))) unsigned int*)(&Vs[BSEL][c * 8]),  \
          16, 0, 0);                                                            \
    }                                                                           \
  }

  STAGE(0, 0);
  __syncthreads();

  for (int it = 0; it < 64; ++it) {
    int cur = it & 1;
    if (it < 63) STAGE(it + 1, cur ^ 1);

    s16x8 kc0[4], kc1[4], vb[8];
    #pragma unroll
    for (int dc = 0; dc < 4; ++dc) {
      kc0[dc] = *(const s16x8*)(&Ks[cur][r * 128 + (((dc * 4 + g) ^ (r & 7)) << 3)]);
      kc1[dc] = *(const s16x8*)(&Ks[cur][(16 + r) * 128 + (((dc * 4 + g) ^ (r & 7)) << 3)]);
    }
    #pragma unroll
    for (int dt = 0; dt < 8; ++dt)
      vb[dt] = *(const s16x8*)(&Vs[cur][(dt * 16 + r) * 32 + ((g ^ (r & 3)) << 3)]);

    f32x4 sc0[2], sc1[2];
    #pragma unroll
    for (int gq = 0; gq < 2; ++gq) { sc0[gq] = (f32x4){0.f,0.f,0.f,0.f}; sc1[gq] = (f32x4){0.f,0.f,0.f,0.f}; }
    __builtin_amdgcn_s_setprio(1);
    #pragma unroll
    for (int dc = 0; dc < 4; ++dc) {
      #pragma unroll
      for (int gq = 0; gq < 2; ++gq) {
        sc0[gq] = MFMA_BF16(qa[gq][dc], kc0[dc], sc0[gq], 0, 0, 0);
        sc1[gq] = MFMA_BF16(qa[gq][dc], kc1[dc], sc1[gq], 0, 0, 0);
      }
    }
    __builtin_amdgcn_s_setprio(0);

    float p0[2][4], p1[2][4];
    #pragma unroll
    for (int gq = 0; gq < 2; ++gq) {
      float mx[4];
      #pragma unroll
      for (int j = 0; j < 4; ++j) mx[j] = rowmax16(fmaxf(sc0[gq][j], sc1[gq][j]));
      bool nd = (mx[0] > m[gq][0] + 8.f) | (mx[1] > m[gq][1] + 8.f)
              | (mx[2] > m[gq][2] + 8.f) | (mx[3] > m[gq][3] + 8.f);
      if (__any(nd)) {
        #pragma unroll
        for (int j = 0; j < 4; ++j) {
          float mn = fmaxf(m[gq][j], mx[j]);
          float alpha = __expf(m[gq][j] - mn);
          m[gq][j] = mn;
          l[gq][j] *= alpha;
          #pragma unroll
          for (int dt = 0; dt < 8; ++dt) o[gq][dt][j] *= alpha;
        }
      }
      #pragma unroll
      for (int j = 0; j < 4; ++j) {
        p0[gq][j] = __expf(sc0[gq][j] - m[gq][j]);
        p1[gq][j] = __expf(sc1[gq][j] - m[gq][j]);
        l[gq][j] += p0[gq][j] + p1[gq][j];
      }
      #pragma unroll
      for (int j = 0; j < 4; ++j) {
        Ps[w][gq * 16 + g * 4 + j][r]      = f2bf(p0[gq][j]);
        Ps[w][gq * 16 + g * 4 + j][16 + r] = f2bf(p1[gq][j]);
      }
    }
    asm volatile("s_waitcnt lgkmcnt(0)" ::: "memory");
    __builtin_amdgcn_sched_barrier(0);
    s16x8 pa0 = *(const s16x8*)(&Ps[w][r][g * 8]);
    s16x8 pa1 = *(const s16x8*)(&Ps[w][16 + r][g * 8]);
    __builtin_amdgcn_s_setprio(1);
    #pragma unroll
    for (int dt = 0; dt < 8; ++dt) {
      o[0][dt] = MFMA_BF16(pa0, vb[dt], o[0][dt], 0, 0, 0);
      o[1][dt] = MFMA_BF16(pa1, vb[dt], o[1][dt], 0, 0, 0);
    }
    __builtin_amdgcn_s_setprio(0);
    __syncthreads();
  }

  #pragma unroll
  for (int gq = 0; gq < 2; ++gq) {
    float linv[4];
    #pragma unroll
    for (int j = 0; j < 4; ++j) linv[j] = 1.0f / rowsum16(l[gq][j]);
    short* ob = out + ((size_t)(b * S + qrow0 + gq * 16)) * 2048 + h * 128;
    #pragma unroll
    for (int dt = 0; dt < 8; ++dt)
      #pragma unroll
      for (int j = 0; j < 4; ++j)
        ob[(size_t)(g * 4 + j) * 2048 + dt * 16 + r] = f2bf(o[gq][dt][j] * linv[j]);
  }
#undef STAGE
}

extern "C" void kernel_launch(void* const* d_in, const int* in_sizes, int n_in,
                              void* d_out, int out_size, void* d_ws, size_t ws_size,
                              hipStream_t stream) {
  const float* x   = (const float*)d_in[0];
  const float* n1w = (const float*)d_in[1];
  const float* wq  = (const float*)d_in[2];
  const float* wk  = (const float*)d_in[3];
  const float* wv  = (const float*)d_in[4];
  const float* wo  = (const float*)d_in[5];
  const float* n2w = (const float*)d_in[6];
  const float* w1  = (const float*)d_in[7];
  const float* w2  = (const float*)d_in[8];
  const float* w3  = (const float*)d_in[9];
  float* out = (float*)d_out;   // doubles as fp32 xmid buffer
  char* ws = (char*)d_ws;
  const size_t MB = 1ull << 20;
  short* wqb  = (short*)(ws);              //  8 MB (pre-scaled by 1/sqrt(128))
  short* wob  = (short*)(ws + 8 * MB);     //  8 MB
  short* w1b  = (short*)(ws + 16 * MB);    // 32 MB
  short* w2b  = (short*)(ws + 48 * MB);    // 32 MB
  short* w3b  = (short*)(ws + 80 * MB);    // 32 MB
  short* wkvb = (short*)(ws + 112 * MB);   //  1 MB [256,2048]
  short* h1   = (short*)(ws + 113 * MB);   // 16 MB
  short* gbuf = (short*)(ws + 129 * MB);   // 64 MB; overlays qb/kvb/vtb
  short* qb   = (short*)(ws + 129 * MB);   // 16 MB
  short* kvb  = (short*)(ws + 145 * MB);   //  2 MB
  short* vtb  = (short*)(ws + 147 * MB);   //  1 MB

  const float qscale = 0.08838834764831845f;  // 1/sqrt(128) folded into wq
  cvt_kernel<<<2048, 256, 0, stream>>>(wq, wqb, 4194304, qscale);
  cvt_kernel<<<128,  256, 0, stream>>>(wk, wkvb, 262144, 1.0f);
  cvt_kernel<<<128,  256, 0, stream>>>(wv, wkvb + 262144, 262144, 1.0f);
  cvt_kernel<<<2048, 256, 0, stream>>>(wo, wob, 4194304, 1.0f);
  cvt_kernel<<<8192, 256, 0, stream>>>(w1, w1b, 16777216, 1.0f);
  cvt_kernel<<<8192, 256, 0, stream>>>(w2, w2b, 16777216, 1.0f);
  cvt_kernel<<<8192, 256, 0, stream>>>(w3, w3b, 16777216, 1.0f);

  rmsnorm_kernel<<<4096, 256, 0, stream>>>(x, n1w, h1);
  gemm128_kernel<0><<<dim3(16, 32), 256, 0, stream>>>(h1, wqb, qb, nullptr, 4096, 2048, 2048);
  gemm_bt_kernel<0><<<dim3(2, 32), 256, 0, stream>>>(h1, wkvb, kvb, nullptr, 4096, 256, 2048);
  transpose_v_kernel<<<dim3(32, 2, 2), 256, 0, stream>>>(kvb, vtb);
  attn_kernel<<<dim3(16, 16, 2), 256, 0, stream>>>(qb, kvb, vtb, h1);
  gemm128_kernel<1><<<dim3(16, 32), 256, 0, stream>>>(h1, wob, out, x, 4096, 2048, 2048);
  rmsnorm_kernel<<<4096, 256, 0, stream>>>(out, n2w, h1);
  gemm_w13_kernel<<<dim3(64, 32), 256, 0, stream>>>(h1, w1b, w3b, gbuf, 4096, 8192, 2048);
  gemm128_kernel<1><<<dim3(16, 32), 256, 0, stream>>>(gbuf, w2b, out, out, 4096, 2048, 8192);
}